// Round 7
// baseline (273.847 us; speedup 1.0000x reference)
//
#include <hip/hip_runtime.h>
#include <hip/hip_bf16.h>
#include <math.h>

#define IN_C 128
#define HC   256
#define CH   64
#define NEG  0.2f

typedef __attribute__((ext_vector_type(8))) short short8;
typedef __attribute__((ext_vector_type(4))) float f32x4;

__device__ __forceinline__ float lrelu(float v) { return v > 0.f ? v : NEG * v; }

__device__ __forceinline__ unsigned short f2bf(float f) {
    __hip_bfloat16 h = __float2bfloat16(f);
    return *reinterpret_cast<unsigned short*>(&h);
}
__device__ __forceinline__ unsigned pack2(float lo, float hi) {
    return (unsigned)f2bf(lo) | ((unsigned)f2bf(hi) << 16);
}

// fma of 8 bf16 (packed in uint4) into fp32 acc[8]
__device__ __forceinline__ void fma8(float* acc, float w, const uint4 u) {
    acc[0] = fmaf(w, __uint_as_float(u.x << 16),        acc[0]);
    acc[1] = fmaf(w, __uint_as_float(u.x & 0xFFFF0000u), acc[1]);
    acc[2] = fmaf(w, __uint_as_float(u.y << 16),        acc[2]);
    acc[3] = fmaf(w, __uint_as_float(u.y & 0xFFFF0000u), acc[3]);
    acc[4] = fmaf(w, __uint_as_float(u.z << 16),        acc[4]);
    acc[5] = fmaf(w, __uint_as_float(u.z & 0xFFFF0000u), acc[5]);
    acc[6] = fmaf(w, __uint_as_float(u.w << 16),        acc[6]);
    acc[7] = fmaf(w, __uint_as_float(u.w & 0xFFFF0000u), acc[7]);
}

// ---------------- W fp32 -> bf16 preconversion (once per launch) ----------------
__global__ void k_wconv(const float* __restrict__ W, short* __restrict__ Wb, int n)
{
    int i = blockIdx.x * 256 + threadIdx.x;   // handles 4 floats
    if (i * 4 >= n) return;
    const float4 v = *(const float4*)&W[i * 4];
    uint2 pk;
    pk.x = pack2(v.x, v.y);
    pk.y = pack2(v.z, v.w);
    *(uint2*)&Wb[i * 4] = pk;
}

// ---------------- MFMA GEMM: xl = x @ W^T (bf16), fused a_src/a_dst epilogue ----
// block = 256 thr / 64 rows; wave w owns rows [w*16,w*16+16).
// Wb staged to LDS (pure uint4 copies), 16B chunks XOR-swizzled: slot = c ^ (row&15).
// xlb output layout: [H][N][64] bf16 (per-head planes for the phased gather).
// asrc/adst transposed: [H][N].
__global__ void __launch_bounds__(256) k_gemm(
    const float* __restrict__ x, const short* __restrict__ Wb,
    const float* __restrict__ att_src, const float* __restrict__ att_dst,
    __hip_bfloat16* __restrict__ xlb, float* __restrict__ asrc,
    float* __restrict__ adst, int N)
{
    __shared__ short Wlds[256 * 128];   // 64 KB

    const int t    = threadIdx.x;
    const int wv   = t >> 6;
    const int lane = t & 63;
    const int m    = lane & 15;
    const int quad = lane >> 4;
    const int r0   = blockIdx.x * 64 + wv * 16;

    // ---- stage Wb into LDS, swizzled; 4096 16B chunks, coalesced global reads ----
#pragma unroll
    for (int i = 0; i < 16; ++i) {
        const int g   = t + 256 * i;          // chunk id
        const int row = g >> 4;
        const int c   = g & 15;
        const uint4 v = *(const uint4*)&Wb[g * 8];
        *(uint4*)&Wlds[row * 128 + ((c ^ (row & 15)) * 8)] = v;
    }
    __syncthreads();

    // ---- K-loop: 4 chunks of 32; 16 col-tiles of 16 ----
    f32x4 acc[16];
#pragma unroll
    for (int tc = 0; tc < 16; ++tc) acc[tc] = (f32x4){0.f, 0.f, 0.f, 0.f};

    const int arow = min(r0 + m, N - 1);
    const float* xrow = &x[(size_t)arow * IN_C];

#pragma unroll
    for (int kc = 0; kc < IN_C; kc += 32) {
        union { short8 v; unsigned u[4]; } a;
        const float4 xa = *(const float4*)&xrow[kc + quad * 8];
        const float4 xb = *(const float4*)&xrow[kc + quad * 8 + 4];
        a.u[0] = pack2(xa.x, xa.y); a.u[1] = pack2(xa.z, xa.w);
        a.u[2] = pack2(xb.x, xb.y); a.u[3] = pack2(xb.z, xb.w);
        const int kchunk = (kc >> 3) + quad;          // 16B chunk index in row
        const int slotoff = ((kchunk ^ m) * 8);
#pragma unroll
        for (int tc = 0; tc < 16; ++tc) {
            const short8 b = *(const short8*)&Wlds[(tc * 16 + m) * 128 + slotoff];
            acc[tc] = __builtin_amdgcn_mfma_f32_16x16x32_bf16(a.v, b, acc[tc], 0, 0, 0);
        }
    }

    // ---- epilogue: store bf16 xl (per-head planes) + fused logits (transposed) ----
    float as_l[16], ad_l[16];
#pragma unroll
    for (int tc = 0; tc < 16; ++tc) {
        as_l[tc] = att_src[tc * 16 + m];
        ad_l[tc] = att_dst[tc * 16 + m];
    }

#pragma unroll
    for (int i = 0; i < 4; ++i) {
        const int grow = r0 + quad * 4 + i;
        const bool ok = grow < N;
        float ps[4] = {0.f, 0.f, 0.f, 0.f};
        float pd[4] = {0.f, 0.f, 0.f, 0.f};
#pragma unroll
        for (int tc = 0; tc < 16; ++tc) {
            const float v = acc[tc][i];
            if (ok) {
                const int hd = tc >> 2;
                const int ch = (tc & 3) * 16 + m;
                xlb[((size_t)hd * N + grow) * CH + ch] = __float2bfloat16(v);
            }
            ps[tc >> 2] = fmaf(v, as_l[tc], ps[tc >> 2]);
            pd[tc >> 2] = fmaf(v, ad_l[tc], pd[tc >> 2]);
        }
#pragma unroll
        for (int msk = 1; msk < 16; msk <<= 1) {
#pragma unroll
            for (int hd = 0; hd < 4; ++hd) {
                ps[hd] += __shfl_xor(ps[hd], msk);
                pd[hd] += __shfl_xor(pd[hd], msk);
            }
        }
        if (m == 0 && ok) {
#pragma unroll
            for (int hd = 0; hd < 4; ++hd) {
                asrc[(size_t)hd * N + grow] = ps[hd];
                adst[(size_t)hd * N + grow] = pd[hd];
            }
        }
    }
}

// ---------------- degree histogram; atomic return value = within-segment rank ----------------
__global__ void k_deg(const int* __restrict__ ei, int* __restrict__ deg,
                      int* __restrict__ perm, int E)
{
    int e = blockIdx.x * 256 + threadIdx.x;
    if (e >= E) return;
    int d = ei[E + e];
    perm[e] = atomicAdd(&deg[d], 1);
}

// ---------------- exclusive scan (2-level, multi-block) ----------------
__global__ void k_scan1(const int* __restrict__ deg, int* __restrict__ offs,
                        int* __restrict__ partials, int N)
{
    __shared__ int sh[1024];
    int t = threadIdx.x, b = blockIdx.x;
    int idx = b * 1024 + t;
    int v = (idx < N) ? deg[idx] : 0;
    sh[t] = v; __syncthreads();
    for (int off = 1; off < 1024; off <<= 1) {
        int u = (t >= off) ? sh[t - off] : 0;
        __syncthreads();
        sh[t] += u;
        __syncthreads();
    }
    if (idx < N) offs[idx] = sh[t] - v;
    if (t == 1023) partials[b] = sh[t];
}

__global__ void k_scan2(int* __restrict__ partials, int nparts)
{
    __shared__ int sh[1024];
    int t = threadIdx.x;
    int v = (t < nparts) ? partials[t] : 0;
    sh[t] = v; __syncthreads();
    for (int off = 1; off < 1024; off <<= 1) {
        int u = (t >= off) ? sh[t - off] : 0;
        __syncthreads();
        sh[t] += u;
        __syncthreads();
    }
    if (t < nparts) partials[t] = sh[t] - v;  // exclusive
}

__global__ void k_scan3(int* __restrict__ offs, const int* __restrict__ partials,
                        int N, int E)
{
    int t = threadIdx.x, b = blockIdx.x;
    int idx = b * 1024 + t;
    if (idx < N) offs[idx] += partials[b];
    if (idx == 0) offs[N] = E;
}

// ---------------- atomic-free CSR placement ----------------
__global__ void k_place(const int* __restrict__ ei, const int* __restrict__ perm,
                        const int* __restrict__ offs, int* __restrict__ csr_src, int E)
{
    int e = blockIdx.x * 256 + threadIdx.x;
    if (e >= E) return;
    int s = ei[e];
    int d = ei[E + e];
    csr_src[offs[d] + perm[e]] = s;
}

// ---------------- gather-aggregate: per-head phases, 8-lane group per edge row ----
// gridDim.y = head (y-blocks dispatch after x -> temporal phase separation, so
// the concurrent src footprint is one 6.4 MB head-plane, mostly L2-resident).
// wave per (node, head); lane = e8*8 + li; group e8 handles edge slot q=e8+8k;
// lane li covers bf16 channels [li*8, li*8+8). Slot 0 = self loop.
__global__ void __launch_bounds__(256) k_agg(
    const __hip_bfloat16* __restrict__ xlb, const float* __restrict__ asrc,
    const float* __restrict__ adst, const int* __restrict__ offs,
    const int* __restrict__ csr_src, const float* __restrict__ bias,
    float* __restrict__ out, int N)
{
    const int t    = threadIdx.x;
    const int wv   = t >> 6;
    const int lane = t & 63;
    const int e8   = lane >> 3;
    const int li   = lane & 7;
    const int h    = blockIdx.y;
    const int n    = blockIdx.x * 4 + wv;
    if (n >= N) return;

    const __hip_bfloat16* __restrict__ xh = xlb + (size_t)h * N * CH;
    const float* __restrict__ ah = asrc + (size_t)h * N;

    const float adn = adst[(size_t)h * N + n];
    const int p0  = offs[n];
    const int cnt = offs[n + 1] - p0 + 1;   // + self loop (slot 0)

    float acc[8];
#pragma unroll
    for (int q = 0; q < 8; ++q) acc[q] = 0.f;
    float l = 0.f;

    int q = e8;
    for (; q + 8 < cnt; q += 16) {   // 2 rows in flight per group -> 16 per wave
        const int s0 = (q == 0) ? n : csr_src[p0 + q - 1];
        const int s1 = csr_src[p0 + q + 7];
        const float a0 = ah[s0];
        const float a1 = ah[s1];
        const uint4 u0 = *(const uint4*)&xh[(size_t)s0 * CH + li * 8];
        const uint4 u1 = *(const uint4*)&xh[(size_t)s1 * CH + li * 8];
        const float w0 = __expf(lrelu(a0 + adn));
        const float w1 = __expf(lrelu(a1 + adn));
        l += w0 + w1;
        fma8(acc, w0, u0);
        fma8(acc, w1, u1);
    }
    if (q < cnt) {
        const int s0 = (q == 0) ? n : csr_src[p0 + q - 1];
        const float a0 = ah[s0];
        const uint4 u0 = *(const uint4*)&xh[(size_t)s0 * CH + li * 8];
        const float w0 = __expf(lrelu(a0 + adn));
        l += w0;
        fma8(acc, w0, u0);
    }

    // reduce across the 8 edge-slot groups (lane bits 3,4,5)
#pragma unroll
    for (int msk = 8; msk < 64; msk <<= 1) {
        l += __shfl_xor(l, msk);
#pragma unroll
        for (int z = 0; z < 8; ++z) acc[z] += __shfl_xor(acc[z], msk);
    }
    const float inv = 1.0f / l;

    if (e8 == 0) {   // lanes 0..7 write the head's 64 channels (256 B contiguous)
        const int cbase = h * CH + li * 8;
        const float4 b0 = *(const float4*)&bias[cbase];
        const float4 b1 = *(const float4*)&bias[cbase + 4];
        float4 o0, o1;
        o0.x = acc[0] * inv + b0.x; o0.y = acc[1] * inv + b0.y;
        o0.z = acc[2] * inv + b0.z; o0.w = acc[3] * inv + b0.w;
        o1.x = acc[4] * inv + b1.x; o1.y = acc[5] * inv + b1.y;
        o1.z = acc[6] * inv + b1.z; o1.w = acc[7] * inv + b1.w;
        o0.x = o0.x > 0.f ? o0.x : expm1f(o0.x);
        o0.y = o0.y > 0.f ? o0.y : expm1f(o0.y);
        o0.z = o0.z > 0.f ? o0.z : expm1f(o0.z);
        o0.w = o0.w > 0.f ? o0.w : expm1f(o0.w);
        o1.x = o1.x > 0.f ? o1.x : expm1f(o1.x);
        o1.y = o1.y > 0.f ? o1.y : expm1f(o1.y);
        o1.z = o1.z > 0.f ? o1.z : expm1f(o1.z);
        o1.w = o1.w > 0.f ? o1.w : expm1f(o1.w);
        *(float4*)&out[(size_t)n * HC + cbase]     = o0;
        *(float4*)&out[(size_t)n * HC + cbase + 4] = o1;
    }
}

extern "C" void kernel_launch(void* const* d_in, const int* in_sizes, int n_in,
                              void* d_out, int out_size, void* d_ws, size_t ws_size,
                              hipStream_t stream) {
    const float* x       = (const float*)d_in[0];
    const int*   ei      = (const int*)d_in[1];   // [2][E] int32
    const float* W       = (const float*)d_in[2];
    const float* att_src = (const float*)d_in[3];
    const float* att_dst = (const float*)d_in[4];
    const float* bias    = (const float*)d_in[5];
    float* out = (float*)d_out;

    const int N = in_sizes[0] / IN_C;
    const int E = in_sizes[1] / 2;
    const int W_ELEMS = HC * IN_C;   // 32768

    char* p = (char*)d_ws;
    auto alloc = [&](size_t bytes) -> char* {
        char* q = p;
        p += (bytes + 255) & ~(size_t)255;
        return q;
    };
    __hip_bfloat16* xlb = (__hip_bfloat16*)alloc((size_t)N * HC * 2);
    short* Wb   = (short*)alloc((size_t)W_ELEMS * 2);
    float* asrc = (float*)alloc((size_t)N * 4 * 4);
    float* adst = (float*)alloc((size_t)N * 4 * 4);
    int*   deg  = (int*)alloc((size_t)N * 4);
    int*   offs = (int*)alloc((size_t)(N + 1) * 4);
    int*   perm = (int*)alloc((size_t)E * 4);
    int*   part = (int*)alloc(4096);
    int*   csr  = (int*)alloc((size_t)E * 4);

    hipMemsetAsync(deg, 0, (size_t)N * 4, stream);

    k_wconv<<<(W_ELEMS / 4 + 255) / 256, 256, 0, stream>>>(W, Wb, W_ELEMS);

    k_gemm<<<(N + 63) / 64, 256, 0, stream>>>(x, Wb, att_src, att_dst, xlb, asrc, adst, N);

    k_deg<<<(E + 255) / 256, 256, 0, stream>>>(ei, deg, perm, E);

    const int nb = (N + 1023) / 1024;
    k_scan1<<<nb, 1024, 0, stream>>>(deg, offs, part, N);
    k_scan2<<<1, 1024, 0, stream>>>(part, nb);
    k_scan3<<<nb, 1024, 0, stream>>>(offs, part, N, E);

    k_place<<<(E + 255) / 256, 256, 0, stream>>>(ei, perm, offs, csr, E);

    dim3 agrid((N + 3) / 4, 4, 1);
    k_agg<<<agrid, 256, 0, stream>>>(xlb, asrc, adst, offs, csr, bias, out, N);
}

// Round 9
// 224.571 us; speedup vs baseline: 1.2194x; 1.2194x over previous
//
#include <hip/hip_runtime.h>
#include <hip/hip_bf16.h>
#include <math.h>

#define IN_C 128
#define HC   256
#define CH   64
#define NEG  0.2f

typedef __attribute__((ext_vector_type(8))) short short8;
typedef __attribute__((ext_vector_type(4))) float f32x4;

#define TSTRIDE 264   // shorts; 528 B/row: 16B-aligned, quads map 4-way max on writes

__device__ __forceinline__ float lrelu(float v) { return v > 0.f ? v : NEG * v; }

__device__ __forceinline__ unsigned short f2bf(float f) {
    __hip_bfloat16 h = __float2bfloat16(f);
    return *reinterpret_cast<unsigned short*>(&h);
}
__device__ __forceinline__ unsigned pack2(float lo, float hi) {
    return (unsigned)f2bf(lo) | ((unsigned)f2bf(hi) << 16);
}

// fma of 8 bf16 (packed in uint4) into fp32 acc[8]
__device__ __forceinline__ void fma8(float* acc, float w, const uint4 u) {
    acc[0] = fmaf(w, __uint_as_float(u.x << 16),        acc[0]);
    acc[1] = fmaf(w, __uint_as_float(u.x & 0xFFFF0000u), acc[1]);
    acc[2] = fmaf(w, __uint_as_float(u.y << 16),        acc[2]);
    acc[3] = fmaf(w, __uint_as_float(u.y & 0xFFFF0000u), acc[3]);
    acc[4] = fmaf(w, __uint_as_float(u.z << 16),        acc[4]);
    acc[5] = fmaf(w, __uint_as_float(u.z & 0xFFFF0000u), acc[5]);
    acc[6] = fmaf(w, __uint_as_float(u.w << 16),        acc[6]);
    acc[7] = fmaf(w, __uint_as_float(u.w & 0xFFFF0000u), acc[7]);
}

// ---------------- W fp32 -> bf16 preconversion (once per launch) ----------------
__global__ void k_wconv(const float* __restrict__ W, short* __restrict__ Wb, int n)
{
    int i = blockIdx.x * 256 + threadIdx.x;   // handles 4 floats
    if (i * 4 >= n) return;
    const float4 v = *(const float4*)&W[i * 4];
    uint2 pk;
    pk.x = pack2(v.x, v.y);
    pk.y = pack2(v.z, v.w);
    *(uint2*)&Wb[i * 4] = pk;
}

// ---------------- FUSED: deg-histogram blocks [0,DB) + MFMA GEMM blocks [DB,DB+GB) ----
// deg blocks run concurrently with gemm blocks (no data dependency) -> the
// 800K-atomic histogram hides under MFMA compute instead of serializing.
// GEMM: block = 256 thr / 64 rows; wave w owns rows [w*16,w*16+16).
// Wb staged to LDS swizzled (slot = chunk ^ (row&15)); after the K-loop the
// same LDS is reused (barrier) as a transpose buffer so xlb is written with
// coalesced uint4 stores instead of 64 scalar shorts per thread.
__global__ void __launch_bounds__(256) k_gemm_deg(
    const float* __restrict__ x, const short* __restrict__ Wb,
    const float* __restrict__ att_src, const float* __restrict__ att_dst,
    const int* __restrict__ ei, int* __restrict__ deg, int* __restrict__ perm,
    __hip_bfloat16* __restrict__ xlb, float* __restrict__ asrc,
    float* __restrict__ adst, int N, int E, int DB)
{
    __shared__ short Wlds[256 * 128];   // 64 KB; reused as transpose buffer

    const int t = threadIdx.x;

    if ((int)blockIdx.x < DB) {
        // ---- degree histogram; atomic return value = within-segment rank ----
        const int stride = DB * 256;
        for (int e = blockIdx.x * 256 + t; e < E; e += stride) {
            const int d = ei[E + e];
            perm[e] = atomicAdd(&deg[d], 1);
        }
        return;
    }

    const int bx   = blockIdx.x - DB;
    const int wv   = t >> 6;
    const int lane = t & 63;
    const int m    = lane & 15;
    const int quad = lane >> 4;
    const int r0   = bx * 64 + wv * 16;

    // ---- stage Wb into LDS, swizzled; 4096 16B chunks, coalesced reads ----
#pragma unroll
    for (int i = 0; i < 16; ++i) {
        const int g   = t + 256 * i;          // chunk id
        const int row = g >> 4;
        const int c   = g & 15;
        const uint4 v = *(const uint4*)&Wb[g * 8];
        *(uint4*)&Wlds[row * 128 + ((c ^ (row & 15)) * 8)] = v;
    }
    __syncthreads();

    // ---- K-loop: 4 chunks of 32; 16 col-tiles of 16 ----
    f32x4 acc[16];
#pragma unroll
    for (int tc = 0; tc < 16; ++tc) acc[tc] = (f32x4){0.f, 0.f, 0.f, 0.f};

    const int arow = min(r0 + m, N - 1);
    const float* xrow = &x[(size_t)arow * IN_C];

#pragma unroll
    for (int kc = 0; kc < IN_C; kc += 32) {
        union { short8 v; unsigned u[4]; } a;
        const float4 xa = *(const float4*)&xrow[kc + quad * 8];
        const float4 xb = *(const float4*)&xrow[kc + quad * 8 + 4];
        a.u[0] = pack2(xa.x, xa.y); a.u[1] = pack2(xa.z, xa.w);
        a.u[2] = pack2(xb.x, xb.y); a.u[3] = pack2(xb.z, xb.w);
        const int kchunk = (kc >> 3) + quad;          // 16B chunk index in row
        const int slotoff = ((kchunk ^ m) * 8);
#pragma unroll
        for (int tc = 0; tc < 16; ++tc) {
            const short8 b = *(const short8*)&Wlds[(tc * 16 + m) * 128 + slotoff];
            acc[tc] = __builtin_amdgcn_mfma_f32_16x16x32_bf16(a.v, b, acc[tc], 0, 0, 0);
        }
    }

    // ---- fused attention logits (register/shfl only) ----
    float as_l[16], ad_l[16];
#pragma unroll
    for (int tc = 0; tc < 16; ++tc) {
        as_l[tc] = att_src[tc * 16 + m];
        ad_l[tc] = att_dst[tc * 16 + m];
    }
#pragma unroll
    for (int i = 0; i < 4; ++i) {
        const int grow = r0 + quad * 4 + i;
        const bool ok = grow < N;
        float ps[4] = {0.f, 0.f, 0.f, 0.f};
        float pd[4] = {0.f, 0.f, 0.f, 0.f};
#pragma unroll
        for (int tc = 0; tc < 16; ++tc) {
            const float v = acc[tc][i];
            ps[tc >> 2] = fmaf(v, as_l[tc], ps[tc >> 2]);
            pd[tc >> 2] = fmaf(v, ad_l[tc], pd[tc >> 2]);
        }
#pragma unroll
        for (int msk = 1; msk < 16; msk <<= 1) {
#pragma unroll
            for (int hd = 0; hd < 4; ++hd) {
                ps[hd] += __shfl_xor(ps[hd], msk);
                pd[hd] += __shfl_xor(pd[hd], msk);
            }
        }
        if (m == 0 && ok) {
#pragma unroll
            for (int hd = 0; hd < 4; ++hd) {
                asrc[grow * 4 + hd] = ps[hd];
                adst[grow * 4 + hd] = pd[hd];
            }
        }
    }

    // ---- xlb store via LDS transpose: reuse Wlds (K-loop done) ----
    __syncthreads();   // all waves done reading W
#pragma unroll
    for (int i = 0; i < 4; ++i) {
        const int lrow = wv * 16 + quad * 4 + i;
#pragma unroll
        for (int tc = 0; tc < 16; ++tc)
            Wlds[lrow * TSTRIDE + tc * 16 + m] = (short)f2bf(acc[tc][i]);
    }
    __syncthreads();
    const int r0blk = bx * 64;
#pragma unroll
    for (int k2 = 0; k2 < 8; ++k2) {
        const int c   = t + 256 * k2;
        const int row = c >> 5;
        const int off = c & 31;
        if (r0blk + row < N) {
            const uint4 v = *(const uint4*)&Wlds[row * TSTRIDE + off * 8];
            *(uint4*)&xlb[(size_t)(r0blk + row) * HC + off * 8] = v;
        }
    }
}

// ---------------- exclusive scan (2-level, multi-block) ----------------
__global__ void k_scan1(const int* __restrict__ deg, int* __restrict__ offs,
                        int* __restrict__ partials, int N)
{
    __shared__ int sh[1024];
    int t = threadIdx.x, b = blockIdx.x;
    int idx = b * 1024 + t;
    int v = (idx < N) ? deg[idx] : 0;
    sh[t] = v; __syncthreads();
    for (int off = 1; off < 1024; off <<= 1) {
        int u = (t >= off) ? sh[t - off] : 0;
        __syncthreads();
        sh[t] += u;
        __syncthreads();
    }
    if (idx < N) offs[idx] = sh[t] - v;
    if (t == 1023) partials[b] = sh[t];
}

__global__ void k_scan2(int* __restrict__ partials, int nparts)
{
    __shared__ int sh[1024];
    int t = threadIdx.x;
    int v = (t < nparts) ? partials[t] : 0;
    sh[t] = v; __syncthreads();
    for (int off = 1; off < 1024; off <<= 1) {
        int u = (t >= off) ? sh[t - off] : 0;
        __syncthreads();
        sh[t] += u;
        __syncthreads();
    }
    if (t < nparts) partials[t] = sh[t] - v;  // exclusive
}

__global__ void k_scan3(int* __restrict__ offs, const int* __restrict__ partials,
                        int N, int E)
{
    int t = threadIdx.x, b = blockIdx.x;
    int idx = b * 1024 + t;
    if (idx < N) offs[idx] += partials[b];
    if (idx == 0) offs[N] = E;
}

// ---------------- atomic-free CSR placement ----------------
__global__ void k_place(const int* __restrict__ ei, const int* __restrict__ perm,
                        const int* __restrict__ offs, int* __restrict__ csr_src, int E)
{
    int e = blockIdx.x * 256 + threadIdx.x;
    if (e >= E) return;
    int s = ei[e];
    int d = ei[E + e];
    csr_src[offs[d] + perm[e]] = s;
}

// ---------------- gather-aggregate: single pass, no max-shift (round-6 geometry) ----
// Softmax is shift-invariant; logits bounded (|a| < ~15) -> no max pass needed.
// One wave per node; half-wave per 512B edge row; li covers bf16 ch [li*8,li*8+8).
__global__ void __launch_bounds__(256) k_agg(
    const __hip_bfloat16* __restrict__ xlb, const float* __restrict__ asrc,
    const float* __restrict__ adst, const int* __restrict__ offs,
    const int* __restrict__ csr_src, const float* __restrict__ bias,
    float* __restrict__ out, int N)
{
    const int t    = threadIdx.x;
    const int wv   = t >> 6;
    const int lane = t & 63;
    const int half = lane >> 5;
    const int li   = lane & 31;
    const int h    = li >> 3;
    const int n    = blockIdx.x * 4 + wv;
    if (n >= N) return;

    const float adn = adst[n * 4 + h];
    const int   p0 = offs[n];
    const int   pe = offs[n + 1];

    float acc[8];
#pragma unroll
    for (int q = 0; q < 8; ++q) acc[q] = 0.f;
    float l = 0.f;

    if (half == 0) {   // self loop
        const float w = __expf(lrelu(asrc[n * 4 + h] + adn));
        const uint4 u = *(const uint4*)&xlb[(unsigned)n * HC + li * 8];
        fma8(acc, w, u);
        l = w;
    }

    int p = p0 + half;
    for (; p + 8 <= pe + half; p += 8) {   // 4 edges per half in flight
        const int s0 = csr_src[p];
        const int s1 = csr_src[p + 2];
        const int s2 = csr_src[p + 4];
        const int s3 = csr_src[p + 6];
        const float a0 = asrc[s0 * 4 + h];
        const float a1 = asrc[s1 * 4 + h];
        const float a2 = asrc[s2 * 4 + h];
        const float a3 = asrc[s3 * 4 + h];
        const uint4 u0 = *(const uint4*)&xlb[(unsigned)s0 * HC + li * 8];
        const uint4 u1 = *(const uint4*)&xlb[(unsigned)s1 * HC + li * 8];
        const uint4 u2 = *(const uint4*)&xlb[(unsigned)s2 * HC + li * 8];
        const uint4 u3 = *(const uint4*)&xlb[(unsigned)s3 * HC + li * 8];
        const float w0 = __expf(lrelu(a0 + adn));
        const float w1 = __expf(lrelu(a1 + adn));
        const float w2 = __expf(lrelu(a2 + adn));
        const float w3 = __expf(lrelu(a3 + adn));
        l += (w0 + w1) + (w2 + w3);
        fma8(acc, w0, u0);
        fma8(acc, w1, u1);
        fma8(acc, w2, u2);
        fma8(acc, w3, u3);
    }
    for (; p < pe; p += 2) {
        const int s0 = csr_src[p];
        const float a0 = asrc[s0 * 4 + h];
        const uint4 u0 = *(const uint4*)&xlb[(unsigned)s0 * HC + li * 8];
        const float w0 = __expf(lrelu(a0 + adn));
        l += w0;
        fma8(acc, w0, u0);
    }

    // combine halves
    l += __shfl_xor(l, 32);
#pragma unroll
    for (int q = 0; q < 8; ++q) acc[q] += __shfl_xor(acc[q], 32);
    const float inv = 1.0f / l;

    // epilogue: each half writes 4 of the 8 channels -> coalesced 1KB/row.
    // nontemporal: out is never re-read; keep L2 for the gather.
    const int cbase = li * 8 + half * 4;
    const float4 bv = *(const float4*)&bias[cbase];
    f32x4 o;
    o.x = acc[half * 4 + 0] * inv + bv.x;
    o.y = acc[half * 4 + 1] * inv + bv.y;
    o.z = acc[half * 4 + 2] * inv + bv.z;
    o.w = acc[half * 4 + 3] * inv + bv.w;
    o.x = o.x > 0.f ? o.x : expm1f(o.x);
    o.y = o.y > 0.f ? o.y : expm1f(o.y);
    o.z = o.z > 0.f ? o.z : expm1f(o.z);
    o.w = o.w > 0.f ? o.w : expm1f(o.w);
    __builtin_nontemporal_store(o, (f32x4*)&out[(size_t)n * HC + cbase]);
}

extern "C" void kernel_launch(void* const* d_in, const int* in_sizes, int n_in,
                              void* d_out, int out_size, void* d_ws, size_t ws_size,
                              hipStream_t stream) {
    const float* x       = (const float*)d_in[0];
    const int*   ei      = (const int*)d_in[1];   // [2][E] int32
    const float* W       = (const float*)d_in[2];
    const float* att_src = (const float*)d_in[3];
    const float* att_dst = (const float*)d_in[4];
    const float* bias    = (const float*)d_in[5];
    float* out = (float*)d_out;

    const int N = in_sizes[0] / IN_C;
    const int E = in_sizes[1] / 2;
    const int W_ELEMS = HC * IN_C;   // 32768

    char* p = (char*)d_ws;
    auto alloc = [&](size_t bytes) -> char* {
        char* q = p;
        p += (bytes + 255) & ~(size_t)255;
        return q;
    };
    __hip_bfloat16* xlb = (__hip_bfloat16*)alloc((size_t)N * HC * 2);
    short* Wb   = (short*)alloc((size_t)W_ELEMS * 2);
    float* asrc = (float*)alloc((size_t)N * 4 * 4);
    float* adst = (float*)alloc((size_t)N * 4 * 4);
    int*   deg  = (int*)alloc((size_t)N * 4);
    int*   offs = (int*)alloc((size_t)(N + 1) * 4);
    int*   perm = (int*)alloc((size_t)E * 4);
    int*   part = (int*)alloc(4096);
    int*   csr  = (int*)alloc((size_t)E * 4);

    (void)hipMemsetAsync(deg, 0, (size_t)N * 4, stream);

    k_wconv<<<(W_ELEMS / 4 + 255) / 256, 256, 0, stream>>>(W, Wb, W_ELEMS);

    const int GB = (N + 63) / 64;
    const int DB = (E + 2047) / 2048;   // deg blocks, 8 edges/thread
    k_gemm_deg<<<DB + GB, 256, 0, stream>>>(x, Wb, att_src, att_dst,
                                            ei, deg, perm, xlb, asrc, adst, N, E, DB);

    const int nb = (N + 1023) / 1024;
    k_scan1<<<nb, 1024, 0, stream>>>(deg, offs, part, N);
    k_scan2<<<1, 1024, 0, stream>>>(part, nb);
    k_scan3<<<nb, 1024, 0, stream>>>(offs, part, N, E);

    k_place<<<(E + 255) / 256, 256, 0, stream>>>(ei, perm, offs, csr, E);

    k_agg<<<(N + 3) / 4, 256, 0, stream>>>(xlb, asrc, adst, offs, csr, bias, out, N);
}